// Round 5
// baseline (426.258 us; speedup 1.0000x reference)
//
#include <hip/hip_runtime.h>
#include <math.h>

#define VV 50257
#define Dm 128
#define NN 256
#define RESN 4096
#define SEQ 512
#define TOK 1024  // B*S

using f32x4_t = __attribute__((ext_vector_type(4))) float;
using s16x8_t = __attribute__((ext_vector_type(8))) short;
using u16x4_t = __attribute__((ext_vector_type(4))) unsigned short;
using i32x4_t = __attribute__((ext_vector_type(4))) int;

static __device__ __forceinline__ unsigned short f2bf(float f) {
    unsigned u = __builtin_bit_cast(unsigned, f);
    u += 0x7fffu + ((u >> 16) & 1u);
    return (unsigned short)(u >> 16);
}

// async global->LDS, 16B per lane; LDS dest = uniform base + lane*16 (HW rule)
static __device__ __forceinline__ void gload16(const unsigned short* g, unsigned short* l) {
    __builtin_amdgcn_global_load_lds(
        (const __attribute__((address_space(1))) unsigned int*)g,
        (__attribute__((address_space(3))) unsigned int*)l, 16, 0, 0);
}

// ---------------- pack: invwl/Bp/ac/as float4 tables, transposed cw/opr/opi, LUT ----------------
__global__ void pack_kernel(const float* __restrict__ W, const float* __restrict__ Bp,
                            const float* __restrict__ ac, const float* __restrict__ as_,
                            const float* __restrict__ cw, const float* __restrict__ opr,
                            const float* __restrict__ opi,
                            float4* __restrict__ packed, float* __restrict__ cwT,
                            float* __restrict__ oprT, float* __restrict__ opiT,
                            float2* __restrict__ lutg) {
    int tid = blockIdx.x * 256 + threadIdx.x;  // 0..65535
    int l = tid >> 15;
    int rem = tid & 32767;
    {   // packed[l][d][n]
        int d = rem >> 8, n = rem & 255;
        int src = (l * NN + n) * Dm + d;
        float4 pk;
        pk.x = 1.0f / (1.0f + fabsf(W[src]));
        pk.y = Bp[src];
        pk.z = ac[src];
        pk.w = as_[src];
        packed[tid] = pk;
    }
    {   // cwT[l][k][d] = cw[l][d][k]
        int k = rem >> 7, d = rem & 127;
        cwT[tid] = cw[(l * Dm + d) * (2 * Dm) + k];
    }
    {   // oprT[l][n][d] = opr[l][d][n]
        int n = rem >> 7, d = rem & 127;
        oprT[tid] = opr[(l * Dm + d) * NN + n];
        opiT[tid] = opi[(l * Dm + d) * NN + n];
    }
    if (tid < RESN) {
        float ang = (float)tid * (float)(6.283185307179586476925286766559 / 4096.0);
        lutg[tid] = make_float2(sinf(ang), cosf(ang));
    }
}

// ---------------- one-off: fp32 Wr/Wi -> bf16 ----------------
__global__ void wconv_kernel(const float* __restrict__ Wr, const float* __restrict__ Wi,
                             unsigned short* __restrict__ Wr_bf,
                             unsigned short* __restrict__ Wi_bf) {
    int gid = blockIdx.x * 256 + threadIdx.x;
    int base = gid * 4;
    if (base < VV * Dm) {
        float4 r = *(const float4*)(Wr + base);
        float4 w = *(const float4*)(Wi + base);
        *(u16x4_t*)(Wr_bf + base) = (u16x4_t){f2bf(r.x), f2bf(r.y), f2bf(r.z), f2bf(r.w)};
        *(u16x4_t*)(Wi_bf + base) = (u16x4_t){f2bf(w.x), f2bf(w.y), f2bf(w.z), f2bf(w.w)};
    }
}

// ---------------- fused middle: embed + 2x(xc -> theta/LUT-reduce -> proj) per token ----------------
__global__ void __launch_bounds__(256) mid_kernel(const int* __restrict__ ids,
                                                  const float* __restrict__ emb,
                                                  const float* __restrict__ cwT,
                                                  const float* __restrict__ cb,
                                                  const float4* __restrict__ packed,
                                                  const float2* __restrict__ lutg,
                                                  const float* __restrict__ oprT,
                                                  const float* __restrict__ opiT,
                                                  unsigned short* __restrict__ x_bf) {
    __shared__ float2 lut[RESN];        // 32 KB
    __shared__ float xs[2][256];        // x = [xr|xi] per token
    __shared__ float xcp[2][2][128];    // xc k-half partials
    __shared__ float xc_s[2][128];
    __shared__ float cs_s[2][256], sn_s[2][256];

    int tid = threadIdx.x;
    int t0 = blockIdx.x * 2;

    // LUT global->LDS (float4 = 2 entries)
    const float4* lg = (const float4*)lutg;
    float4* ldst = (float4*)lut;
#pragma unroll
    for (int i = 0; i < 8; i++) ldst[tid + i * 256] = lg[tid + i * 256];
    // embed gather
#pragma unroll
    for (int j = 0; j < 2; j++) xs[j][tid] = emb[(size_t)ids[t0 + j] * 256 + tid];
    __syncthreads();

    int h = tid >> 7, d = tid & 127;
    float tv[2];
#pragma unroll
    for (int j = 0; j < 2; j++) tv[j] = (float)((t0 + j) & (SEQ - 1)) * 1.61803398874989485f;
    const float SC = (float)(4096.0 / 6.283185307179586476925286766559);

    for (int l = 0; l < 2; l++) {
        // ---- xc = x @ cw[l].T + cb[l]  (k-halves split across thread groups) ----
        const float* cwb = cwT + l * 32768;
#pragma unroll
        for (int j = 0; j < 2; j++) {
            float acc = 0.f;
#pragma unroll 8
            for (int k = h * 128; k < h * 128 + 128; k++)
                acc = fmaf(xs[j][k], cwb[k * 128 + d], acc);
            xcp[j][h][d] = acc;
        }
        __syncthreads();
        xc_s[h][d] = xcp[h][0][d] + xcp[h][1][d] + cb[l * 128 + d];
        __syncthreads();
        // ---- theta + LUT + reduce over d: thread = n ----
        const float4* pk = packed + (size_t)(l * Dm) * NN + tid;
        float cs[2] = {0, 0}, sn[2] = {0, 0};
        for (int dd = 0; dd < 128; dd++) {
            float4 p = pk[(size_t)dd * NN];
#pragma unroll
            for (int j = 0; j < 2; j++) {
                float th = fmaf(xc_s[j][dd], p.x, p.y) + tv[j];
                int idx = ((int)floorf(th * SC)) & (RESN - 1);
                float2 scv = lut[idx];
                cs[j] = fmaf(scv.y, p.z, cs[j]);  // cos * attn_cos
                sn[j] = fmaf(scv.x, p.w, sn[j]);  // sin * attn_sin
            }
        }
#pragma unroll
        for (int j = 0; j < 2; j++) {
            cs_s[j][tid] = cs[j];
            sn_s[j][tid] = sn[j];
        }
        __syncthreads();
        // ---- proj: x_new = silu(sum @ op.T); h=0 -> xr from cs, h=1 -> xi from sn ----
        const float* wb = (h == 0 ? oprT : opiT) + l * 32768;
        const float(*ps)[256] = (h == 0) ? cs_s : sn_s;
        float acc[2] = {0, 0};
        for (int n = 0; n < 256; n++) {
            float wv = wb[n * 128 + d];
#pragma unroll
            for (int j = 0; j < 2; j++) acc[j] = fmaf(ps[j][n], wv, acc[j]);
        }
        __syncthreads();  // all reads of xs done; safe to overwrite
#pragma unroll
        for (int j = 0; j < 2; j++) {
            float v = acc[j];
            xs[j][tid] = v / (1.0f + expf(-v));  // silu; note h*128+d == tid
        }
        __syncthreads();
    }
    // ---- emit bf16 A operand for final GEMM ----
#pragma unroll
    for (int j = 0; j < 2; j++) x_bf[(size_t)(t0 + j) * 256 + tid] = f2bf(xs[j][tid]);
}

// ---------------- final complex GEMM + magnitude (2-acc scheme, 3 blocks/CU) -----
// Direct accumulation: accL += xr·Wr + xi·(-Wi)  (lr),  accI += xi·Wr + xr·Wi  (li)
// -Wi via bf16 sign-bit XOR on the B-fragment in registers (exact negation).
// Halves acc VGPRs (128->64) vs the 4-GEMM form -> ~150 VGPR -> 3 blocks/CU (12 waves/CU)
// for latency hiding; LDS 48 KB x 3 = 144 <= 160 KB. Same MFMA count / staging / swizzles.
// Depth-2 prefetch: prologue stages kc=0,1; waits: 6,6,6,0.
__global__ void __launch_bounds__(256, 3) final_kernel(const unsigned short* __restrict__ x_bf,
                                                       const unsigned short* __restrict__ Wr_bf,
                                                       const unsigned short* __restrict__ Wi_bf,
                                                       float* __restrict__ out) {
    __shared__ unsigned short lds[2][12288];  // 2 x 24KB
    int tid = threadIdx.x;
    // bijective XCD swizzle (6288 = 8*786), t fastest within an XCD's chunk
    int wg = blockIdx.x;
    int wp = (wg & 7) * 786 + (wg >> 3);
    int vb = wp >> 3, tb = wp & 7;
    int v0 = vb * 64, t0 = tb * 128;

    int wv = tid >> 6, lane = tid & 63;
    int wm = wv >> 1, wn = wv & 1;
    int quad = lane >> 4, t16 = lane & 15;

    // ---- staging lane mapping (per-lane global source, linear LDS dest) ----
    int r_loc = lane >> 2;                       // row within a 16-row gload instruction
    int csw = (lane & 3) ^ ((lane >> 3) & 3);    // pre-swizzled source chunk (16B units)
    const unsigned short* srcA0 = x_bf + (size_t)(t0 + 32 * wv + r_loc) * 256 + csw * 8;
    const unsigned short* srcA1 = srcA0 + 16 * 256;
    int vv_ = v0 + 16 * wv + r_loc;
    if (vv_ > VV - 1) vv_ = VV - 1;              // clamp OOB v rows (dup loads, never stored)
    const unsigned short* srcWr = Wr_bf + (size_t)vv_ * 128 + csw * 8;
    const unsigned short* srcWi = Wi_bf + (size_t)vv_ * 128 + csw * 8;

    // ---- read-side constants ----
    int rsw = (t16 >> 1) & 3;
    int rdA = (wm * 64 + t16) * 32 + ((quad ^ rsw) << 3);  // +im*512; Ai region +4096
    int rdB = (wn * 32 + t16) * 32 + ((quad ^ rsw) << 3);  // +in*512; Wr +8192, Wi +10240

    f32x4_t accL[4][2], accI[4][2];
#pragma unroll
    for (int im = 0; im < 4; im++)
#pragma unroll
        for (int in = 0; in < 2; in++) {
            accL[im][in] = (f32x4_t){0.f, 0.f, 0.f, 0.f};
            accI[im][in] = (f32x4_t){0.f, 0.f, 0.f, 0.f};
        }

    const i32x4_t NEG = {(int)0x80008000, (int)0x80008000, (int)0x80008000, (int)0x80008000};

    // 6 gload_lds per wave per phase: 2x Ar, 2x Ai, 1x Wr, 1x Wi
#define STAGE(b, kc)                                                             \
    {                                                                            \
        const int ko = (kc) * 32;                                                \
        unsigned short* bb = lds[(b)];                                           \
        gload16(srcA0 + ko, bb + wv * 1024);                                     \
        gload16(srcA1 + ko, bb + wv * 1024 + 512);                               \
        gload16(srcA0 + 128 + ko, bb + 4096 + wv * 1024);                        \
        gload16(srcA1 + 128 + ko, bb + 4096 + wv * 1024 + 512);                  \
        gload16(srcWr + ko, bb + 8192 + wv * 512);                               \
        gload16(srcWi + ko, bb + 10240 + wv * 512);                              \
    }

    STAGE(0, 0);
    STAGE(1, 1);  // depth-2 prologue: 12 in flight
#pragma unroll
    for (int kc = 0; kc < 4; kc++) {
        if (kc < 3) {
            asm volatile("s_waitcnt vmcnt(6)" ::: "memory");  // chunk kc landed (kc+1 in flight)
        } else {
            asm volatile("s_waitcnt vmcnt(0)" ::: "memory");
        }
        __builtin_amdgcn_s_barrier();           // all waves' chunk-kc loads landed
        __builtin_amdgcn_sched_barrier(0);      // pin ds_reads AFTER the cross-wave sync
        const unsigned short* B = lds[kc & 1];
        s16x8_t ar[4], ai[4], fr[2], fi[2], fni[2];
#pragma unroll
        for (int im = 0; im < 4; im++) {
            ar[im] = *(const s16x8_t*)(B + rdA + im * 512);
            ai[im] = *(const s16x8_t*)(B + 4096 + rdA + im * 512);
        }
#pragma unroll
        for (int in = 0; in < 2; in++) {
            fr[in] = *(const s16x8_t*)(B + 8192 + rdB + in * 512);
            fi[in] = *(const s16x8_t*)(B + 10240 + rdB + in * 512);
            fni[in] = __builtin_bit_cast(s16x8_t,
                          __builtin_bit_cast(i32x4_t, fi[in]) ^ NEG);  // -Wi (exact bf16 negate)
        }
#pragma unroll
        for (int im = 0; im < 4; im++)
#pragma unroll
            for (int in = 0; in < 2; in++) {
                accL[im][in] = __builtin_amdgcn_mfma_f32_16x16x32_bf16(ai[im], fni[in],
                                                                      accL[im][in], 0, 0, 0);
                accL[im][in] = __builtin_amdgcn_mfma_f32_16x16x32_bf16(ar[im], fr[in],
                                                                      accL[im][in], 0, 0, 0);
                accI[im][in] = __builtin_amdgcn_mfma_f32_16x16x32_bf16(ar[im], fi[in],
                                                                      accI[im][in], 0, 0, 0);
                accI[im][in] = __builtin_amdgcn_mfma_f32_16x16x32_bf16(ai[im], fr[in],
                                                                      accI[im][in], 0, 0, 0);
            }
        __builtin_amdgcn_s_barrier();  // all reads of this buffer done before restage
        if (kc < 2) STAGE(kc & 1, kc + 2);
    }
#undef STAGE

    // --- epilogue: magnitude + store ---
#pragma unroll
    for (int im = 0; im < 4; im++) {
        int trow = t0 + wm * 64 + im * 16 + quad * 4;
#pragma unroll
        for (int in = 0; in < 2; in++) {
            int v = v0 + wn * 32 + in * 16 + t16;
            if (v < VV) {
#pragma unroll
                for (int r = 0; r < 4; r++) {
                    float lr = accL[im][in][r];
                    float li = accI[im][in][r];
                    out[(size_t)(trow + r) * VV + v] = sqrtf(fmaf(lr, lr, fmaf(li, li, 1e-8f)));
                }
            }
        }
    }
}

extern "C" void kernel_launch(void* const* d_in, const int* in_sizes, int n_in,
                              void* d_out, int out_size, void* d_ws, size_t ws_size,
                              hipStream_t stream) {
    const int* ids   = (const int*)d_in[0];
    const float* emb = (const float*)d_in[1];
    const float* cw  = (const float*)d_in[2];
    const float* cb  = (const float*)d_in[3];
    const float* W   = (const float*)d_in[4];
    const float* Bp  = (const float*)d_in[5];
    const float* ac  = (const float*)d_in[6];
    const float* as_ = (const float*)d_in[7];
    const float* opr = (const float*)d_in[8];
    const float* opi = (const float*)d_in[9];
    const float* Wr  = (const float*)d_in[10];
    const float* Wi  = (const float*)d_in[11];
    float* out = (float*)d_out;

    char* ws = (char*)d_ws;
    float4* packed  = (float4*)(ws + (6u << 20));            // 1 MB (2x128x256 float4)
    float*  cwT     = (float*)(ws + (7u << 20));             // 256 KB
    float*  oprT    = (float*)(ws + (7u << 20) + (256u << 10));
    float*  opiT    = (float*)(ws + (7u << 20) + (512u << 10));
    float2* lutg    = (float2*)(ws + (7u << 20) + (768u << 10));  // 32 KB
    unsigned short* x_bf  = (unsigned short*)(ws + (8u  << 20));  // 512 KB (1024x256 bf16)
    unsigned short* Wr_bf = (unsigned short*)(ws + (9u  << 20));  // 12.27 MB (50257x128 bf16)
    unsigned short* Wi_bf = (unsigned short*)(ws + (22u << 20));  // 12.27 MB

    pack_kernel<<<256, 256, 0, stream>>>(W, Bp, ac, as_, cw, opr, opi,
                                         packed, cwT, oprT, opiT, lutg);
    wconv_kernel<<<(VV * Dm / 4 + 255) / 256, 256, 0, stream>>>(Wr, Wi, Wr_bf, Wi_bf);
    mid_kernel<<<TOK / 2, 256, 0, stream>>>(ids, emb, cwT, cb, packed, lutg,
                                            oprT, opiT, x_bf);
    final_kernel<<<dim3(786 * 8), 256, 0, stream>>>(x_bf, Wr_bf, Wi_bf, out);
}